// Round 13
// baseline (427.763 us; speedup 1.0000x reference)
//
#include <hip/hip_runtime.h>
#include <hip/hip_bf16.h>

// bf16 round-to-nearest-even pack / unpack (bit ops)
__device__ __forceinline__ unsigned f2bf_rne(float f) {
    unsigned u = __float_as_uint(f);
    u += 0x7FFFu + ((u >> 16) & 1u);
    return u >> 16;
}
__device__ __forceinline__ float bf_lo(unsigned p) { return __uint_as_float(p << 16); }
__device__ __forceinline__ float bf_hi(unsigned p) { return __uint_as_float(p & 0xFFFF0000u); }
template <int I> __device__ __forceinline__ float bfsel(unsigned p) {
    return (I == 0) ? bf_lo(p) : bf_hi(p);
}

// ---------------------------------------------------------------------------
// init: zero cnt (all blocks); block 0: we dots; block 1: W2T transpose
// ---------------------------------------------------------------------------
__global__ __launch_bounds__(256)
void init_kernel(int* __restrict__ cnt, int n,
                 const float* __restrict__ We1, const float* __restrict__ ae1v,
                 const float* __restrict__ We2, const float* __restrict__ ae2v,
                 float* __restrict__ we1, float* __restrict__ we2,
                 const float* __restrict__ W2, float* __restrict__ W2T) {
    int i = blockIdx.x * 256 + threadIdx.x;
    if (i < n) cnt[i] = 0;
    if (blockIdx.x == 0 && threadIdx.x >= 64 && threadIdx.x < 128) {
        int t = threadIdx.x - 64;
        const float* W = (t < 32) ? We1 : We2;
        const float* a = (t < 32) ? ae1v : ae2v;
        float* o       = (t < 32) ? we1 : we2;
        int k = t & 31;
        float s = 0.f;
        for (int c = 0; c < 64; ++c) s += W[k * 64 + c] * a[c];
        o[k] = s;
    }
    if (blockIdx.x == 1) {
        // W2T[k][c] = W2[c][k]  (64x64)
        for (int t = threadIdx.x; t < 4096; t += 256) {
            int k = t >> 6, c = t & 63;
            W2T[t] = W2[c * 64 + k];
        }
    }
}

// ---------------------------------------------------------------------------
// streaming edge pass: 8 lanes per edge, 2 edges per slot (64 edges/block).
// dot(ea, we) both layers + in-degree count.
// pack8[e] = {src<<16|dst, bf16(ae1)|bf16(ae2)<<16}   (n < 65536)
// ---------------------------------------------------------------------------
__global__ __launch_bounds__(256)
void edge_pass_kernel(const float4* __restrict__ ea, const int* __restrict__ eidx,
                      const float* __restrict__ we1g, const float* __restrict__ we2g,
                      int* __restrict__ cnt, uint2* __restrict__ pack8, int E) {
    int tid = threadIdx.x;
    int q = tid & 7;
    int slot = tid >> 3;                      // 0..31
    int base = blockIdx.x * 64;
    float4 w1 = ((const float4*)we1g)[q];
    float4 w2 = ((const float4*)we2g)[q];
#pragma unroll
    for (int h = 0; h < 2; ++h) {
        int e = base + slot + h * 32;
        if (e < E) {                          // uniform across the 8-lane group
            float4 v = ea[(size_t)e * 8 + q];
            float a1 = v.x * w1.x + v.y * w1.y + v.z * w1.z + v.w * w1.w;
            float a2 = v.x * w2.x + v.y * w2.y + v.z * w2.z + v.w * w2.w;
#pragma unroll
            for (int off = 1; off < 8; off <<= 1) {
                a1 += __shfl_xor(a1, off, 64);
                a2 += __shfl_xor(a2, off, 64);
            }
            if (q == 0) {
                unsigned src = (unsigned)eidx[e];
                unsigned dst = (unsigned)eidx[E + e];
                atomicAdd(&cnt[dst], 1);
                pack8[e] = make_uint2((src << 16) | dst,
                                      f2bf_rne(a1) | (f2bf_rne(a2) << 16));
            }
        }
    }
}

// ---------------------------------------------------------------------------
// scan stage A: per-256-chunk sums
// ---------------------------------------------------------------------------
__global__ __launch_bounds__(256)
void scanA_kernel(const int* __restrict__ cnt, int* __restrict__ bsum, int n) {
    int idx = blockIdx.x * 256 + threadIdx.x;
    int v = (idx < n) ? cnt[idx] : 0;
#pragma unroll
    for (int off = 32; off >= 1; off >>= 1) v += __shfl_xor(v, off, 64);
    __shared__ int ws[4];
    int lane = threadIdx.x & 63, wid = threadIdx.x >> 6;
    if (lane == 0) ws[wid] = v;
    __syncthreads();
    if (threadIdx.x == 0) bsum[blockIdx.x] = ws[0] + ws[1] + ws[2] + ws[3];
}

// ---------------------------------------------------------------------------
// scan stage C: block offset by direct bsum sum, in-chunk scan -> row_ptr
// + cursor (for scatter-side placement atomics)
// ---------------------------------------------------------------------------
__global__ __launch_bounds__(256)
void scanC_kernel(const int* __restrict__ cnt, const int* __restrict__ bsum,
                  int* __restrict__ row_ptr, int* __restrict__ cursor, int n, int E) {
    __shared__ int ws[4];
    __shared__ int woff[4];
    __shared__ int bws[4];
    int lane = threadIdx.x & 63, wid = threadIdx.x >> 6;
    int partial = 0;
    for (int j = threadIdx.x; j < blockIdx.x; j += 256) partial += bsum[j];
#pragma unroll
    for (int off = 32; off >= 1; off >>= 1) partial += __shfl_xor(partial, off, 64);
    if (lane == 0) bws[wid] = partial;
    __syncthreads();
    int boff = bws[0] + bws[1] + bws[2] + bws[3];
    int idx = blockIdx.x * 256 + threadIdx.x;
    int v = (idx < n) ? cnt[idx] : 0;
    int s = v;
#pragma unroll
    for (int off = 1; off < 64; off <<= 1) {
        int t = __shfl_up(s, off, 64);
        if (lane >= off) s += t;
    }
    if (lane == 63) ws[wid] = s;
    __syncthreads();
    if (threadIdx.x == 0) {
        int run = 0;
        for (int w = 0; w < 4; ++w) { int t = ws[w]; woff[w] = run; run += t; }
    }
    __syncthreads();
    if (idx < n) {
        int ex = boff + woff[wid] + s - v;
        row_ptr[idx] = ex;
        cursor[idx] = ex;
    }
    if (idx == 0) row_ptr[n] = E;
}

// ---------------------------------------------------------------------------
// scatter pass: sequential 8B read, cursor-atomic placement, scattered 8B
// store. s_rec[pos] = {src, ae1|ae2}
// ---------------------------------------------------------------------------
__global__ __launch_bounds__(256)
void scatter_kernel(const uint2* __restrict__ pack8, int* __restrict__ cursor,
                    uint2* __restrict__ s_rec, int E) {
    int e = blockIdx.x * 256 + threadIdx.x;
    if (e >= E) return;
    uint2 p = pack8[e];
    int dst = (int)(p.x & 0xFFFFu);
    unsigned src = p.x >> 16;
    int pos = atomicAdd(&cursor[dst], 1);
    s_rec[pos] = make_uint2(src, p.y);
}

// ---------------------------------------------------------------------------
// H = X @ W + attn logit dots. W transposed+padded in LDS (b128 reads).
// H stored bf16.
// ---------------------------------------------------------------------------
template <int INC>
__global__ __launch_bounds__(256)
void gemm_kernel(const float* __restrict__ X, const float* __restrict__ W,
                 const float* __restrict__ asv, const float* __restrict__ adv,
                 __hip_bfloat16* __restrict__ H, float* __restrict__ a_src,
                 float* __restrict__ a_dst, int n) {
    constexpr int LDW = INC + 4;
    __shared__ float Wl[64 * LDW];
    for (int t = threadIdx.x; t < INC * 64; t += 256) {
        int k = t >> 6, c = t & 63;
        Wl[c * LDW + k] = W[t];
    }
    __syncthreads();
    int wid = threadIdx.x >> 6, lane = threadIdx.x & 63;
    int i = blockIdx.x * 4 + wid;
    if (i >= n) return;
    const float4* xr = (const float4*)(X + (size_t)i * INC);
    const float4* wr = (const float4*)(Wl + lane * LDW);
    float acc = 0.f;
#pragma unroll
    for (int k4 = 0; k4 < INC / 4; ++k4) {
        float4 xv = xr[k4];
        float4 wv = wr[k4];
        acc += xv.x * wv.x + xv.y * wv.y + xv.z * wv.z + xv.w * wv.w;
    }
    H[(size_t)i * 64 + lane] = __float2bfloat16(acc);
    float s = acc * asv[lane];
    float d = acc * adv[lane];
#pragma unroll
    for (int off = 32; off >= 1; off >>= 1) {
        s += __shfl_xor(s, off, 64);
        d += __shfl_xor(d, off, 64);
    }
    if (lane == 0) { a_src[i] = s; a_dst[i] = d; }
}

// bf16x4 (ushort4, 8B) -> 4 floats
__device__ __forceinline__ float4 bf4_to_f4(ushort4 u) {
    float4 f;
    f.x = __uint_as_float((unsigned)u.x << 16);
    f.y = __uint_as_float((unsigned)u.y << 16);
    f.z = __uint_as_float((unsigned)u.z << 16);
    f.w = __uint_as_float((unsigned)u.w << 16);
    return f;
}

// ---------------------------------------------------------------------------
// fused aggregation (single-pass softmax, LDS weight broadcast, 4-slot x
// 16-quad gather). FUSE_GEMM2: h2 = relu'd row @ W2 via W2T (lane-private
// float4 rows, L1-resident) — no separate gemm2 kernel, no f32 round-trip.
// ---------------------------------------------------------------------------
template <int AEIDX, bool RELU, bool FUSE_GEMM2>
__global__ __launch_bounds__(256)
void agg_fused_kernel(const int* __restrict__ row_ptr, const uint2* __restrict__ s_rec,
                      const float* __restrict__ a_srcv, const float* __restrict__ a_dstv,
                      const ushort4* __restrict__ H4, const float* __restrict__ bias,
                      float* __restrict__ out,
                      const float* __restrict__ W2T, const float* __restrict__ as2v,
                      const float* __restrict__ ad2v, __hip_bfloat16* __restrict__ H2,
                      float* __restrict__ a_src2, float* __restrict__ a_dst2, int n) {
    __shared__ uint2 wl[4][128];
    __shared__ float4 rowl[4][16];
    int wid = threadIdx.x >> 6, lane = threadIdx.x & 63;
    int i = blockIdx.x * 4 + wid;
    if (i >= n) return;
    int start = row_ptr[i], end = row_ptr[i + 1];
    int deg = end - start;
    float adst = a_dstv[i];

    // ---- phase 1: one pass -> w = exp(leakyrelu(logit)), den, ae-sum ----
    float w0 = 0.f, w1 = 0.f;
    int src0 = 0, src1 = 0;
    float aeloc = 0.f, dloc = 0.f;
    {
        int j = start + lane;
        if (j < end) {
            uint2 r = s_rec[j];
            float ae = bfsel<AEIDX>(r.y);
            src0 = (int)r.x;
            float a = a_srcv[src0] + adst + ae;
            a = a > 0.f ? a : 0.2f * a;
            w0 = __expf(a);
            aeloc += ae; dloc += w0;
        }
    }
    if (deg > 64) {
        int j = start + 64 + lane;
        if (j < end) {
            uint2 r = s_rec[j];
            float ae = bfsel<AEIDX>(r.y);
            src1 = (int)r.x;
            float a = a_srcv[src1] + adst + ae;
            a = a > 0.f ? a : 0.2f * a;
            w1 = __expf(a);
            aeloc += ae; dloc += w1;
        }
    }
    for (int base = start + 128; base < end; base += 64) {   // rare spill
        int j = base + lane;
        if (j < end) {
            uint2 r = s_rec[j];
            float ae = bfsel<AEIDX>(r.y);
            int s = (int)r.x;
            float a = a_srcv[s] + adst + ae;
            a = a > 0.f ? a : 0.2f * a;
            aeloc += ae; dloc += __expf(a);
        }
    }
#pragma unroll
    for (int off = 32; off >= 1; off >>= 1) {
        aeloc += __shfl_xor(aeloc, off, 64);
        dloc  += __shfl_xor(dloc, off, 64);
    }
    float ael = aeloc / (float)(deg > 0 ? deg : 1);
    float als = a_srcv[i] + adst + ael;
    als = als > 0.f ? als : 0.2f * als;
    float wself = __expf(als);
    float inv = 1.f / (dloc + wself + 1e-16f);

    wl[wid][lane]      = make_uint2((unsigned)src0, __float_as_uint(w0));
    wl[wid][64 + lane] = make_uint2((unsigned)src1, __float_as_uint(w1));

    // ---- phase 2: gather. wave = 4 edge-slots x 16 channel-quads ----
    int sub = lane >> 4;
    int c4  = lane & 15;
    float4 acc = make_float4(0.f, 0.f, 0.f, 0.f);
    int mainCnt = deg < 128 ? deg : 128;
#pragma unroll 4
    for (int r = 0; r < mainCnt; r += 4) {
        uint2 sw = wl[wid][r + sub];
        float w = __uint_as_float(sw.y);
        float4 hv = bf4_to_f4(H4[(size_t)((sw.x << 4) | (unsigned)c4)]);
        acc.x += w * hv.x; acc.y += w * hv.y;
        acc.z += w * hv.z; acc.w += w * hv.w;
    }
    for (int j = start + 128; j < end; j += 4) {   // rare spill: recompute w
        int jj = j + sub;
        if (jj < end) {
            uint2 r = s_rec[jj];
            float ae = bfsel<AEIDX>(r.y);
            int s = (int)r.x;
            float a = a_srcv[s] + adst + ae;
            a = a > 0.f ? a : 0.2f * a;
            float w = __expf(a);
            float4 hv = bf4_to_f4(H4[(size_t)(((unsigned)s << 4) | (unsigned)c4)]);
            acc.x += w * hv.x; acc.y += w * hv.y;
            acc.z += w * hv.z; acc.w += w * hv.w;
        }
    }
#pragma unroll
    for (int off = 16; off <= 32; off <<= 1) {
        acc.x += __shfl_xor(acc.x, off, 64);
        acc.y += __shfl_xor(acc.y, off, 64);
        acc.z += __shfl_xor(acc.z, off, 64);
        acc.w += __shfl_xor(acc.w, off, 64);
    }
    float4 hv = bf4_to_f4(H4[(size_t)(((unsigned)i << 4) | (unsigned)c4)]);
    float4 bv = ((const float4*)bias)[c4];
    float4 o;
    o.x = (acc.x + wself * hv.x) * inv + bv.x;
    o.y = (acc.y + wself * hv.y) * inv + bv.y;
    o.z = (acc.z + wself * hv.z) * inv + bv.z;
    o.w = (acc.w + wself * hv.w) * inv + bv.w;
    if (RELU) {
        o.x = fmaxf(o.x, 0.f); o.y = fmaxf(o.y, 0.f);
        o.z = fmaxf(o.z, 0.f); o.w = fmaxf(o.w, 0.f);
    }

    if (!FUSE_GEMM2) {
        if (sub == 0) ((float4*)out)[(size_t)i * 16 + c4] = o;
        return;
    }

    // ---- fused gemm2 via W2T: h2[lane] = sum_c row[c]*W2T[lane][c] ----
    if (sub == 0) rowl[wid][c4] = o;
    const float4* w2t4 = (const float4*)W2T;     // [64][16] float4 rows
    float acc2 = 0.f;
#pragma unroll
    for (int qq = 0; qq < 16; ++qq) {
        float4 rq = rowl[wid][qq];               // LDS broadcast
        float4 wv = w2t4[lane * 16 + qq];        // lane-private, L1-hit
        acc2 += rq.x * wv.x + rq.y * wv.y + rq.z * wv.z + rq.w * wv.w;
    }
    H2[(size_t)i * 64 + lane] = __float2bfloat16(acc2);
    float s2 = acc2 * as2v[lane];
    float d2 = acc2 * ad2v[lane];
#pragma unroll
    for (int off = 32; off >= 1; off >>= 1) {
        s2 += __shfl_xor(s2, off, 64);
        d2 += __shfl_xor(d2, off, 64);
    }
    if (lane == 0) { a_src2[i] = s2; a_dst2[i] = d2; }
}

// ---------------------------------------------------------------------------
extern "C" void kernel_launch(void* const* d_in, const int* in_sizes, int n_in,
                              void* d_out, int out_size, void* d_ws, size_t ws_size,
                              hipStream_t stream) {
    const float* x        = (const float*)d_in[0];
    const int*   eidx     = (const int*)d_in[1];
    const float* eattr    = (const float*)d_in[2];
    const float* W1       = (const float*)d_in[3];
    const float* We1      = (const float*)d_in[4];
    const float* att_src1 = (const float*)d_in[5];
    const float* att_dst1 = (const float*)d_in[6];
    const float* att_edge1= (const float*)d_in[7];
    const float* b1       = (const float*)d_in[8];
    const float* W2       = (const float*)d_in[9];
    const float* We2      = (const float*)d_in[10];
    const float* att_src2 = (const float*)d_in[11];
    const float* att_dst2 = (const float*)d_in[12];
    const float* att_edge2= (const float*)d_in[13];
    const float* b2       = (const float*)d_in[14];
    float* out = (float*)d_out;

    const int n = in_sizes[0] / 128;    // 50000
    const int E = in_sizes[1] / 2;      // 1600000

    char* ws = (char*)d_ws;
    size_t off = 0;
    auto carve = [&](size_t bytes) {
        char* p = ws + off;
        off = (off + bytes + 255) & ~(size_t)255;
        return p;
    };
    const int nblkScan = (n + 255) / 256;
    float*    we1    = (float*)carve(32 * 4);
    float*    we2    = (float*)carve(32 * 4);
    float*    W2T    = (float*)carve(64 * 64 * 4);
    int*      cnt    = (int*)carve((size_t)n * 4);
    int*      bsum   = (int*)carve((size_t)nblkScan * 4);
    int*      row_ptr= (int*)carve((size_t)(n + 1) * 4);
    int*      cursor = (int*)carve((size_t)n * 4);
    uint2*    pack8  = (uint2*)carve((size_t)E * 8);
    uint2*    s_rec  = (uint2*)carve((size_t)E * 8);
    __hip_bfloat16* bufA = (__hip_bfloat16*)carve((size_t)n * 64 * 2);  // H1 bf16
    __hip_bfloat16* bufB = (__hip_bfloat16*)carve((size_t)n * 64 * 2);  // H2 bf16
    float*    a_src  = (float*)carve((size_t)n * 4);
    float*    a_dst  = (float*)carve((size_t)n * 4);
    float*    a_src2 = (float*)carve((size_t)n * 4);
    float*    a_dst2 = (float*)carve((size_t)n * 4);

    init_kernel<<<nblkScan, 256, 0, stream>>>(cnt, n, We1, att_edge1,
                                              We2, att_edge2, we1, we2, W2, W2T);

    edge_pass_kernel<<<(E + 63) / 64, 256, 0, stream>>>((const float4*)eattr, eidx,
                                                        we1, we2, cnt, pack8, E);
    scanA_kernel<<<nblkScan, 256, 0, stream>>>(cnt, bsum, n);
    scanC_kernel<<<nblkScan, 256, 0, stream>>>(cnt, bsum, row_ptr, cursor, n, E);

    scatter_kernel<<<(E + 255) / 256, 256, 0, stream>>>(pack8, cursor, s_rec, E);

    int ngrid = (n + 3) / 4;
    // layer 1 GEMM
    gemm_kernel<128><<<ngrid, 256, 0, stream>>>(x, W1, att_src1, att_dst1,
                                                bufA, a_src, a_dst, n);
    // layer-1 aggregation + fused layer-2 GEMM
    agg_fused_kernel<0, true, true><<<ngrid, 256, 0, stream>>>(
        row_ptr, s_rec, a_src, a_dst, (const ushort4*)bufA, b1,
        /*out=*/nullptr, W2T, att_src2, att_dst2, bufB, a_src2, a_dst2, n);
    // layer-2 aggregation -> final output
    agg_fused_kernel<1, false, false><<<ngrid, 256, 0, stream>>>(
        row_ptr, s_rec, a_src2, a_dst2, (const ushort4*)bufB, b2,
        out, nullptr, nullptr, nullptr, nullptr, nullptr, nullptr, n);
}

// Round 14
// 271.281 us; speedup vs baseline: 1.5768x; 1.5768x over previous
//
#include <hip/hip_runtime.h>
#include <hip/hip_bf16.h>

// bf16 round-to-nearest-even pack / unpack (bit ops)
__device__ __forceinline__ unsigned f2bf_rne(float f) {
    unsigned u = __float_as_uint(f);
    u += 0x7FFFu + ((u >> 16) & 1u);
    return u >> 16;
}
__device__ __forceinline__ float bf_lo(unsigned p) { return __uint_as_float(p << 16); }
__device__ __forceinline__ float bf_hi(unsigned p) { return __uint_as_float(p & 0xFFFF0000u); }
template <int I> __device__ __forceinline__ float bfsel(unsigned p) {
    return (I == 0) ? bf_lo(p) : bf_hi(p);
}

// ---------------------------------------------------------------------------
// init: zero cnt (all blocks) + we[k] = sum_c We[k][c]*att_edge[c] (block 0)
// ---------------------------------------------------------------------------
__global__ __launch_bounds__(256)
void init_kernel(int* __restrict__ cnt, int n,
                 const float* __restrict__ We1, const float* __restrict__ ae1v,
                 const float* __restrict__ We2, const float* __restrict__ ae2v,
                 float* __restrict__ we1, float* __restrict__ we2) {
    int i = blockIdx.x * 256 + threadIdx.x;
    if (i < n) cnt[i] = 0;
    if (blockIdx.x == 0 && threadIdx.x >= 64 && threadIdx.x < 128) {
        int t = threadIdx.x - 64;
        const float* W = (t < 32) ? We1 : We2;
        const float* a = (t < 32) ? ae1v : ae2v;
        float* o       = (t < 32) ? we1 : we2;
        int k = t & 31;
        float s = 0.f;
        for (int c = 0; c < 64; ++c) s += W[k * 64 + c] * a[c];
        o[k] = s;
    }
}

// ---------------------------------------------------------------------------
// streaming edge pass, 8 lanes per edge (coalesced 16B/lane):
// dot(ea, we) both layers + in-degree rank.
// pack8[e] = {src, bf16(ae1)|bf16(ae2)<<16};  meta[e] = rank<<16 | dst
// ---------------------------------------------------------------------------
__global__ __launch_bounds__(256)
void edge_pass_kernel(const float4* __restrict__ ea, const int* __restrict__ eidx,
                      const float* __restrict__ we1g, const float* __restrict__ we2g,
                      int* __restrict__ cnt, uint2* __restrict__ pack8,
                      unsigned* __restrict__ meta, int E) {
    int tid = threadIdx.x;
    int q = tid & 7;
    int e = blockIdx.x * 32 + (tid >> 3);
    if (e >= E) return;
    float4 w1 = ((const float4*)we1g)[q];
    float4 w2 = ((const float4*)we2g)[q];
    float4 v = ea[(size_t)e * 8 + q];
    float a1 = v.x * w1.x + v.y * w1.y + v.z * w1.z + v.w * w1.w;
    float a2 = v.x * w2.x + v.y * w2.y + v.z * w2.z + v.w * w2.w;
#pragma unroll
    for (int off = 1; off < 8; off <<= 1) {
        a1 += __shfl_xor(a1, off, 64);
        a2 += __shfl_xor(a2, off, 64);
    }
    if (q == 0) {
        int src = eidx[e];
        int dst = eidx[E + e];
        int rk = atomicAdd(&cnt[dst], 1);
        pack8[e] = make_uint2((unsigned)src, f2bf_rne(a1) | (f2bf_rne(a2) << 16));
        meta[e] = ((unsigned)rk << 16) | (unsigned)dst;
    }
}

// ---------------------------------------------------------------------------
// scan stage A: per-256-chunk sums
// ---------------------------------------------------------------------------
__global__ __launch_bounds__(256)
void scanA_kernel(const int* __restrict__ cnt, int* __restrict__ bsum, int n) {
    int idx = blockIdx.x * 256 + threadIdx.x;
    int v = (idx < n) ? cnt[idx] : 0;
#pragma unroll
    for (int off = 32; off >= 1; off >>= 1) v += __shfl_xor(v, off, 64);
    __shared__ int ws[4];
    int lane = threadIdx.x & 63, wid = threadIdx.x >> 6;
    if (lane == 0) ws[wid] = v;
    __syncthreads();
    if (threadIdx.x == 0) bsum[blockIdx.x] = ws[0] + ws[1] + ws[2] + ws[3];
}

// ---------------------------------------------------------------------------
// scan stage C: block offset = direct sum of bsum[0..bid) (nb<=256, cheap),
// then in-chunk scan -> row_ptr. (scanB eliminated)
// ---------------------------------------------------------------------------
__global__ __launch_bounds__(256)
void scanC_kernel(const int* __restrict__ cnt, const int* __restrict__ bsum,
                  int* __restrict__ row_ptr, int n, int E) {
    __shared__ int ws[4];
    __shared__ int woff[4];
    __shared__ int bws[4];
    int lane = threadIdx.x & 63, wid = threadIdx.x >> 6;
    // --- block offset: sum of bsum[j] for j < blockIdx.x ---
    int partial = 0;
    for (int j = threadIdx.x; j < blockIdx.x; j += 256) partial += bsum[j];
#pragma unroll
    for (int off = 32; off >= 1; off >>= 1) partial += __shfl_xor(partial, off, 64);
    if (lane == 0) bws[wid] = partial;
    __syncthreads();
    int boff = bws[0] + bws[1] + bws[2] + bws[3];
    // --- in-chunk exclusive scan ---
    int idx = blockIdx.x * 256 + threadIdx.x;
    int v = (idx < n) ? cnt[idx] : 0;
    int s = v;
#pragma unroll
    for (int off = 1; off < 64; off <<= 1) {
        int t = __shfl_up(s, off, 64);
        if (lane >= off) s += t;
    }
    if (lane == 63) ws[wid] = s;
    __syncthreads();
    if (threadIdx.x == 0) {
        int run = 0;
        for (int w = 0; w < 4; ++w) { int t = ws[w]; woff[w] = run; run += t; }
    }
    __syncthreads();
    if (idx < n) row_ptr[idx] = boff + woff[wid] + s - v;
    if (idx == 0) row_ptr[n] = E;
}

// ---------------------------------------------------------------------------
// scatter pass: sequential 12B read, single scattered 8B store.
// pos = row_ptr[dst] + rank (atomic-free, deterministic)
// ---------------------------------------------------------------------------
__global__ __launch_bounds__(256)
void scatter_kernel(const uint2* __restrict__ pack8, const unsigned* __restrict__ meta,
                    const int* __restrict__ row_ptr, uint2* __restrict__ s_rec, int E) {
    int e = blockIdx.x * 256 + threadIdx.x;
    if (e >= E) return;
    unsigned m = meta[e];
    int dst = (int)(m & 0xFFFFu);
    int rk  = (int)(m >> 16);
    s_rec[row_ptr[dst] + rk] = pack8[e];
}

// ---------------------------------------------------------------------------
// H = X @ W + attn logit dots. W transposed+padded in LDS (b128 reads).
// H stored bf16.
// ---------------------------------------------------------------------------
template <int INC>
__global__ __launch_bounds__(256)
void gemm_kernel(const float* __restrict__ X, const float* __restrict__ W,
                 const float* __restrict__ asv, const float* __restrict__ adv,
                 __hip_bfloat16* __restrict__ H, float* __restrict__ a_src,
                 float* __restrict__ a_dst, int n) {
    constexpr int LDW = INC + 4;
    __shared__ float Wl[64 * LDW];
    for (int t = threadIdx.x; t < INC * 64; t += 256) {
        int k = t >> 6, c = t & 63;
        Wl[c * LDW + k] = W[t];
    }
    __syncthreads();
    int wid = threadIdx.x >> 6, lane = threadIdx.x & 63;
    int i = blockIdx.x * 4 + wid;
    if (i >= n) return;
    const float4* xr = (const float4*)(X + (size_t)i * INC);
    const float4* wr = (const float4*)(Wl + lane * LDW);
    float acc = 0.f;
#pragma unroll
    for (int k4 = 0; k4 < INC / 4; ++k4) {
        float4 xv = xr[k4];
        float4 wv = wr[k4];
        acc += xv.x * wv.x + xv.y * wv.y + xv.z * wv.z + xv.w * wv.w;
    }
    H[(size_t)i * 64 + lane] = __float2bfloat16(acc);
    float s = acc * asv[lane];
    float d = acc * adv[lane];
#pragma unroll
    for (int off = 32; off >= 1; off >>= 1) {
        s += __shfl_xor(s, off, 64);
        d += __shfl_xor(d, off, 64);
    }
    if (lane == 0) { a_src[i] = s; a_dst[i] = d; }
}

// bf16x4 (ushort4, 8B) -> 4 floats
__device__ __forceinline__ float4 bf4_to_f4(ushort4 u) {
    float4 f;
    f.x = __uint_as_float((unsigned)u.x << 16);
    f.y = __uint_as_float((unsigned)u.y << 16);
    f.z = __uint_as_float((unsigned)u.z << 16);
    f.w = __uint_as_float((unsigned)u.w << 16);
    return f;
}

// ---------------------------------------------------------------------------
// fused aggregation (single-pass softmax, LDS weight broadcast, 4-slot x
// 16-quad gather). FUSE_GEMM2: after producing the relu'd output row in
// registers, compute h2 = row @ W2 + logits in the same wave (W2 from
// global, L1-resident; row staged 256B in wave-private LDS) — eliminates
// the separate gemm2 kernel and the bufB round-trip.
// ---------------------------------------------------------------------------
template <int AEIDX, bool RELU, bool FUSE_GEMM2>
__global__ __launch_bounds__(256)
void agg_fused_kernel(const int* __restrict__ row_ptr, const uint2* __restrict__ s_rec,
                      const float* __restrict__ a_srcv, const float* __restrict__ a_dstv,
                      const ushort4* __restrict__ H4, const float* __restrict__ bias,
                      float* __restrict__ out,
                      const float* __restrict__ W2, const float* __restrict__ as2v,
                      const float* __restrict__ ad2v, __hip_bfloat16* __restrict__ H2,
                      float* __restrict__ a_src2, float* __restrict__ a_dst2, int n) {
    __shared__ uint2 wl[4][128];
    __shared__ float4 rowl[4][16];
    int wid = threadIdx.x >> 6, lane = threadIdx.x & 63;
    int i = blockIdx.x * 4 + wid;
    if (i >= n) return;
    int start = row_ptr[i], end = row_ptr[i + 1];
    int deg = end - start;
    float adst = a_dstv[i];

    // ---- phase 1: one pass -> w = exp(leakyrelu(logit)), den, ae-sum ----
    float w0 = 0.f, w1 = 0.f;
    int src0 = 0, src1 = 0;
    float aeloc = 0.f, dloc = 0.f;
    {
        int j = start + lane;
        if (j < end) {
            uint2 r = s_rec[j];
            float ae = bfsel<AEIDX>(r.y);
            src0 = (int)r.x;
            float a = a_srcv[src0] + adst + ae;
            a = a > 0.f ? a : 0.2f * a;
            w0 = __expf(a);
            aeloc += ae; dloc += w0;
        }
    }
    if (deg > 64) {
        int j = start + 64 + lane;
        if (j < end) {
            uint2 r = s_rec[j];
            float ae = bfsel<AEIDX>(r.y);
            src1 = (int)r.x;
            float a = a_srcv[src1] + adst + ae;
            a = a > 0.f ? a : 0.2f * a;
            w1 = __expf(a);
            aeloc += ae; dloc += w1;
        }
    }
    for (int base = start + 128; base < end; base += 64) {   // rare spill
        int j = base + lane;
        if (j < end) {
            uint2 r = s_rec[j];
            float ae = bfsel<AEIDX>(r.y);
            int s = (int)r.x;
            float a = a_srcv[s] + adst + ae;
            a = a > 0.f ? a : 0.2f * a;
            aeloc += ae; dloc += __expf(a);
        }
    }
#pragma unroll
    for (int off = 32; off >= 1; off >>= 1) {
        aeloc += __shfl_xor(aeloc, off, 64);
        dloc  += __shfl_xor(dloc, off, 64);
    }
    float ael = aeloc / (float)(deg > 0 ? deg : 1);
    float als = a_srcv[i] + adst + ael;
    als = als > 0.f ? als : 0.2f * als;
    float wself = __expf(als);
    float inv = 1.f / (dloc + wself + 1e-16f);

    // stage {src, w} in wave-private LDS (slots beyond deg carry w=0)
    wl[wid][lane]      = make_uint2((unsigned)src0, __float_as_uint(w0));
    wl[wid][64 + lane] = make_uint2((unsigned)src1, __float_as_uint(w1));

    // ---- phase 2: gather. wave = 4 edge-slots x 16 channel-quads ----
    int sub = lane >> 4;
    int c4  = lane & 15;
    float4 acc = make_float4(0.f, 0.f, 0.f, 0.f);
    int mainCnt = deg < 128 ? deg : 128;
#pragma unroll 4
    for (int r = 0; r < mainCnt; r += 4) {
        uint2 sw = wl[wid][r + sub];             // 8B LDS broadcast
        float w = __uint_as_float(sw.y);
        float4 hv = bf4_to_f4(H4[(size_t)((sw.x << 4) | (unsigned)c4)]);
        acc.x += w * hv.x; acc.y += w * hv.y;
        acc.z += w * hv.z; acc.w += w * hv.w;
    }
    for (int j = start + 128; j < end; j += 4) {   // rare spill: recompute w
        int jj = j + sub;
        if (jj < end) {
            uint2 r = s_rec[jj];
            float ae = bfsel<AEIDX>(r.y);
            int s = (int)r.x;
            float a = a_srcv[s] + adst + ae;
            a = a > 0.f ? a : 0.2f * a;
            float w = __expf(a);
            float4 hv = bf4_to_f4(H4[(size_t)(((unsigned)s << 4) | (unsigned)c4)]);
            acc.x += w * hv.x; acc.y += w * hv.y;
            acc.z += w * hv.z; acc.w += w * hv.w;
        }
    }
#pragma unroll
    for (int off = 16; off <= 32; off <<= 1) {
        acc.x += __shfl_xor(acc.x, off, 64);
        acc.y += __shfl_xor(acc.y, off, 64);
        acc.z += __shfl_xor(acc.z, off, 64);
        acc.w += __shfl_xor(acc.w, off, 64);
    }
    // self-loop + epilogue: all lanes hold o for channel-quad c4
    float4 hv = bf4_to_f4(H4[(size_t)(((unsigned)i << 4) | (unsigned)c4)]);
    float4 bv = ((const float4*)bias)[c4];
    float4 o;
    o.x = (acc.x + wself * hv.x) * inv + bv.x;
    o.y = (acc.y + wself * hv.y) * inv + bv.y;
    o.z = (acc.z + wself * hv.z) * inv + bv.z;
    o.w = (acc.w + wself * hv.w) * inv + bv.w;
    if (RELU) {
        o.x = fmaxf(o.x, 0.f); o.y = fmaxf(o.y, 0.f);
        o.z = fmaxf(o.z, 0.f); o.w = fmaxf(o.w, 0.f);
    }

    if (!FUSE_GEMM2) {
        if (sub == 0) ((float4*)out)[(size_t)i * 16 + c4] = o;
        return;
    }

    // ---- fused gemm2: h2[k] = sum_c row[c] * W2[c][k], logits, bf16 H2 ----
    if (sub == 0) rowl[wid][c4] = o;             // wave-private 256B stage
    float acc2 = 0.f;
#pragma unroll
    for (int q = 0; q < 16; ++q) {
        float4 rq = rowl[wid][q];                // LDS broadcast (b128)
        acc2 += rq.x * W2[(q * 4 + 0) * 64 + lane];   // coalesced, L1-hit
        acc2 += rq.y * W2[(q * 4 + 1) * 64 + lane];
        acc2 += rq.z * W2[(q * 4 + 2) * 64 + lane];
        acc2 += rq.w * W2[(q * 4 + 3) * 64 + lane];
    }
    H2[(size_t)i * 64 + lane] = __float2bfloat16(acc2);
    float s2 = acc2 * as2v[lane];
    float d2 = acc2 * ad2v[lane];
#pragma unroll
    for (int off = 32; off >= 1; off >>= 1) {
        s2 += __shfl_xor(s2, off, 64);
        d2 += __shfl_xor(d2, off, 64);
    }
    if (lane == 0) { a_src2[i] = s2; a_dst2[i] = d2; }
}

// ---------------------------------------------------------------------------
extern "C" void kernel_launch(void* const* d_in, const int* in_sizes, int n_in,
                              void* d_out, int out_size, void* d_ws, size_t ws_size,
                              hipStream_t stream) {
    const float* x        = (const float*)d_in[0];
    const int*   eidx     = (const int*)d_in[1];
    const float* eattr    = (const float*)d_in[2];
    const float* W1       = (const float*)d_in[3];
    const float* We1      = (const float*)d_in[4];
    const float* att_src1 = (const float*)d_in[5];
    const float* att_dst1 = (const float*)d_in[6];
    const float* att_edge1= (const float*)d_in[7];
    const float* b1       = (const float*)d_in[8];
    const float* W2       = (const float*)d_in[9];
    const float* We2      = (const float*)d_in[10];
    const float* att_src2 = (const float*)d_in[11];
    const float* att_dst2 = (const float*)d_in[12];
    const float* att_edge2= (const float*)d_in[13];
    const float* b2       = (const float*)d_in[14];
    float* out = (float*)d_out;

    const int n = in_sizes[0] / 128;    // 50000
    const int E = in_sizes[1] / 2;      // 1600000

    char* ws = (char*)d_ws;
    size_t off = 0;
    auto carve = [&](size_t bytes) {
        char* p = ws + off;
        off = (off + bytes + 255) & ~(size_t)255;
        return p;
    };
    const int nblkScan = (n + 255) / 256;
    float*    we1    = (float*)carve(32 * 4);
    float*    we2    = (float*)carve(32 * 4);
    int*      cnt    = (int*)carve((size_t)n * 4);
    int*      bsum   = (int*)carve((size_t)nblkScan * 4);
    int*      row_ptr= (int*)carve((size_t)(n + 1) * 4);
    uint2*    pack8  = (uint2*)carve((size_t)E * 8);
    unsigned* meta   = (unsigned*)carve((size_t)E * 4);
    uint2*    s_rec  = (uint2*)carve((size_t)E * 8);
    __hip_bfloat16* bufA = (__hip_bfloat16*)carve((size_t)n * 64 * 2);  // H1 bf16
    __hip_bfloat16* bufB = (__hip_bfloat16*)carve((size_t)n * 64 * 2);  // H2 bf16
    float*    a_src  = (float*)carve((size_t)n * 4);
    float*    a_dst  = (float*)carve((size_t)n * 4);
    float*    a_src2 = (float*)carve((size_t)n * 4);
    float*    a_dst2 = (float*)carve((size_t)n * 4);

    init_kernel<<<nblkScan, 256, 0, stream>>>(cnt, n, We1, att_edge1,
                                              We2, att_edge2, we1, we2);

    edge_pass_kernel<<<(E + 31) / 32, 256, 0, stream>>>((const float4*)eattr, eidx,
                                                        we1, we2, cnt, pack8, meta, E);
    scanA_kernel<<<nblkScan, 256, 0, stream>>>(cnt, bsum, n);
    scanC_kernel<<<nblkScan, 256, 0, stream>>>(cnt, bsum, row_ptr, n, E);

    scatter_kernel<<<(E + 255) / 256, 256, 0, stream>>>(pack8, meta, row_ptr, s_rec, E);

    int ngrid = (n + 3) / 4;
    // layer 1 GEMM
    gemm_kernel<128><<<ngrid, 256, 0, stream>>>(x, W1, att_src1, att_dst1,
                                                bufA, a_src, a_dst, n);
    // layer-1 aggregation + fused layer-2 GEMM (relu'd row -> H2, logits2)
    agg_fused_kernel<0, true, true><<<ngrid, 256, 0, stream>>>(
        row_ptr, s_rec, a_src, a_dst, (const ushort4*)bufA, b1,
        /*out=*/nullptr, W2, att_src2, att_dst2, bufB, a_src2, a_dst2, n);
    // layer-2 aggregation -> final output
    agg_fused_kernel<1, false, false><<<ngrid, 256, 0, stream>>>(
        row_ptr, s_rec, a_src2, a_dst2, (const ushort4*)bufB, b2,
        out, nullptr, nullptr, nullptr, nullptr, nullptr, nullptr, n);
}